// Round 9
// baseline (106.464 us; speedup 1.0000x reference)
//
#include <hip/hip_runtime.h>

#define N_PTS 32768
#define M_Q   8192
#define C_F   256
#define PS    4                  // point-range splits
#define RNG   (N_PTS / PS)       // 8192 points per range
#define PAIRS (RNG / 2)          // 4096 point-pairs per range
#define QW    8                  // queries per wave
#define NW    4                  // waves per block
#define QBL   (QW * NW)          // 32 queries per block
#define NSL   2                  // chunk slots per lane (chunk = 64 pts)
#define NQB   (M_Q / QBL)        // 256 query blocks per side
#define MU    1e-3f              // rigorous e-vs-(d*-a2) pruning margin

using v2f = __attribute__((ext_vector_type(2))) float;

__device__ __forceinline__ float rn_mul(float a, float b) { return __fmul_rn(a, b); }
__device__ __forceinline__ float rn_add(float a, float b) { return __fadd_rn(a, b); }
__device__ __forceinline__ float rfl(float x) {
    return __int_as_float(__builtin_amdgcn_readfirstlane(__float_as_int(x)));
}

// exact lexicographic (d,i) insert into running top-2 pair
__device__ __forceinline__ void ins_lex(float d, int i, float& b1, int& j1,
                                        float& b2, int& j2) {
    bool lt1 = (d < b1) || (d == b1 && i < j1);
    bool lt2 = (d < b2) || (d == b2 && i < j2);
    b2 = lt1 ? b1 : (lt2 ? d : b2);
    j2 = lt1 ? j1 : (lt2 ? i : j2);
    b1 = lt1 ? d : b1;
    j1 = lt1 ? i : j1;
}

// reduced insert: caller guarantees (d,i) >=lex current b1 (sorted-pair merge)
__device__ __forceinline__ void ins_lex2(float d, int i, float& b2, int& j2) {
    bool lt2 = (d < b2) || (d == b2 && i < j2);
    b2 = lt2 ? d : b2;
    j2 = lt2 ? i : j2;
}

// merge two value-pairs (each a1<=a2) -> two smallest overall
__device__ __forceinline__ void vpair_merge(float& a1, float& a2, float b1, float b2) {
    float n1 = fminf(a1, b1);
    float n2 = fminf(fmaxf(a1, b1), fminf(a2, b2));
    a1 = n1; a2 = n2;
}

// Pack point-pairs in SoA-pair form: rec[pair] = {x0,x1,y0,y1},{z0,z1,w0,w1}
// w = exact numpy b2 = (x*x + y*y) + z*z, plain rounded ops.
__global__ __launch_bounds__(256) void pack_pairs(const float* __restrict__ c0,
                                                  const float* __restrict__ c1,
                                                  float4* __restrict__ pts4) {
    int t = blockIdx.x * blockDim.x + threadIdx.x;   // 0..32767 pairs (both sides)
    int side = t >> 14;                              // 16384 pairs per side
    int pr = t & 16383;
    const float* p = (side ? c1 : c0) + (size_t)pr * 6;
    float x0 = p[0], y0 = p[1], z0 = p[2];
    float x1 = p[3], y1 = p[4], z1 = p[5];
    float w0 = rn_add(rn_add(rn_mul(x0, x0), rn_mul(y0, y0)), rn_mul(z0, z0));
    float w1 = rn_add(rn_add(rn_mul(x1, x1), rn_mul(y1, y1)), rn_mul(z1, z1));
    size_t b = ((size_t)side * 16384 + pr) * 2;
    pts4[b]     = make_float4(x0, x1, y0, y1);
    pts4[b + 1] = make_float4(z0, z1, w0, w1);
}

// Pass 1: packed-fp32 e-space chunk minima (3 pk_fma + 2 min per 2 pairs).
// Pass 2: exact-numpy rescan of surviving 64-pt chunks, lex top-2.
__global__ __launch_bounds__(256) void pool_scan(
    const float* __restrict__ sc0, const float* __restrict__ sc1,
    const float4* __restrict__ pts4, int4* __restrict__ part)
{
    int bid  = blockIdx.x;            // 2 * NQB * PS = 2048
    int side = bid >> 10;
    int r    = bid & 1023;
    int qblk = r >> 2;                // 0..255
    int ps   = r & (PS - 1);          // 0..3
    const float* sc = side ? sc1 : sc0;

    int tid  = threadIdx.x;
    int wave = tid >> 6;
    int lane = tid & 63;
    int q0   = qblk * QBL + wave * QW;              // absolute query (within side)
    const float4* Pg4 = pts4 + ((size_t)side * (N_PTS / 2) + ps * PAIRS) * 2;

    // wave-uniform query scalars: premultiplied (-2x,-2y,-2z) + exact a2
    float ax2[QW], ay2[QW], az2[QW], a2[QW];
#pragma unroll
    for (int q = 0; q < QW; ++q) {
        int qq = q0 + q;
        float x = rfl(sc[qq * 3 + 0]);
        float y = rfl(sc[qq * 3 + 1]);
        float z = rfl(sc[qq * 3 + 2]);
        a2[q]  = rfl(rn_add(rn_add(rn_mul(x, x), rn_mul(y, y)), rn_mul(z, z)));
        ax2[q] = rfl(-2.0f * x);     // exact scaling
        ay2[q] = rfl(-2.0f * y);
        az2[q] = rfl(-2.0f * z);
    }

    float m[NSL][QW];
#pragma unroll
    for (int s = 0; s < NSL; ++s)
#pragma unroll
        for (int q = 0; q < QW; ++q) m[s][q] = __int_as_float(0x7f800000);

    // ---- Pass 1: stream pairs from global (L2-resident), packed math ----
#pragma unroll
    for (int s = 0; s < NSL; ++s) {
#pragma unroll 4
        for (int j = 0; j < 32; ++j) {
            int pr = s * 2048 + j * 64 + lane;       // pair within range
            float4 A = Pg4[pr * 2];                  // {x0,x1,y0,y1}
            float4 B = Pg4[pr * 2 + 1];              // {z0,z1,w0,w1}
            v2f px = { A.x, A.y };
            v2f py = { A.z, A.w };
            v2f pz = { B.x, B.y };
            v2f pw = { B.z, B.w };
#pragma unroll
            for (int q = 0; q < QW; ++q) {
                // e = b2 - 2*dot, two points at once (v_pk_fma_f32)
                v2f e = az2[q] * pz + (ay2[q] * py + (ax2[q] * px + pw));
                m[s][q] = fminf(m[s][q], fminf(e.x, e.y));
            }
        }
    }

    // ---- beta per query: 2nd-smallest chunk-min over this range ----
    float beta[QW];
#pragma unroll
    for (int q = 0; q < QW; ++q) {
        float p1 = fminf(m[0][q], m[1][q]);
        float p2 = fmaxf(m[0][q], m[1][q]);
#pragma unroll
        for (int off = 1; off < 64; off <<= 1) {
            float o1 = __shfl_xor(p1, off);
            float o2 = __shfl_xor(p2, off);
            vpair_merge(p1, p2, o1, o2);
        }
        beta[q] = rfl(p2) + MU;
    }

    // ---- Pass 2: exact rescan of surviving chunks ----
    float D1[QW], D2[QW];
    int   I1[QW], I2[QW];
#pragma unroll
    for (int q = 0; q < QW; ++q) {
        D1[q] = __int_as_float(0x7f800000); D2[q] = D1[q];
        I1[q] = 0x7fffffff; I2[q] = 0x7fffffff;
    }
    int jj = lane >> 1, tt = lane & 1;   // rescan mapping: 2 lanes per pair
#pragma unroll
    for (int s = 0; s < NSL; ++s) {
#pragma unroll
        for (int q = 0; q < QW; ++q) {
            unsigned long long fm = __ballot(m[s][q] <= beta[q]);
            while (fm) {                       // ~2 fires per (q)
                int lf = (int)__builtin_ctzll(fm);
                fm &= fm - 1;
                int pr = s * 2048 + jj * 64 + lf;
                float4 A = Pg4[pr * 2];
                float4 B = Pg4[pr * 2 + 1];
                float x = tt ? A.y : A.x;
                float y = tt ? A.w : A.z;
                float z = tt ? B.y : B.x;
                float w = tt ? B.w : B.z;
                float ax = -0.5f * ax2[q];     // exact recovery of original coord
                float ay = -0.5f * ay2[q];
                float az = -0.5f * az2[q];
                float dot = __builtin_fmaf(az, z,
                             __builtin_fmaf(ay, y, rn_mul(ax, x)));
                float dd = __builtin_fmaf(-2.0f, dot, rn_add(a2[q], w));
                int gi = ps * RNG + pr * 2 + tt;
                ins_lex(dd, gi, D1[q], I1[q], D2[q], I2[q]);
            }
        }
    }

    // butterfly lex-merge across 64 lanes (sorted-pair: 2nd insert reduced)
#pragma unroll
    for (int off = 1; off < 64; off <<= 1) {
#pragma unroll
        for (int q = 0; q < QW; ++q) {
            float od1 = __shfl_xor(D1[q], off); int oi1 = __shfl_xor(I1[q], off);
            float od2 = __shfl_xor(D2[q], off); int oi2 = __shfl_xor(I2[q], off);
            ins_lex(od1, oi1, D1[q], I1[q], D2[q], I2[q]);
            ins_lex2(od2, oi2, D2[q], I2[q]);
        }
    }
    if (lane == 0) {
#pragma unroll
        for (int q = 0; q < QW; ++q) {
            int qg = side * M_Q + q0 + q;
            part[qg * PS + ps] = make_int4(__float_as_int(D1[q]), I1[q],
                                           __float_as_int(D2[q]), I2[q]);
        }
    }
}

// Merge the PS partials per query (exact lex), gather feature rows.
__global__ __launch_bounds__(256) void merge_gather(
    const float* __restrict__ src, const float* __restrict__ tgt,
    const int4* __restrict__ part, float* __restrict__ out)
{
    __shared__ int sidx[8];

    int bid  = blockIdx.x;            // 2 * M_Q/8 = 2048
    int side = bid >> 10;
    int qb   = bid & 1023;
    const float* feats = side ? tgt : src;
    int tid = threadIdx.x;
    int q0  = qb * 8;

    if (tid < 8) {
        int qg = side * M_Q + q0 + tid;
        int4 p0 = part[qg * PS + 0];
        float b1 = __int_as_float(p0.x), b2 = __int_as_float(p0.z);
        int   j1 = p0.y,                 j2 = p0.w;
#pragma unroll
        for (int sp = 1; sp < PS; ++sp) {
            int4 p = part[qg * PS + sp];
            ins_lex(__int_as_float(p.x), p.y, b1, j1, b2, j2);
            ins_lex2(__int_as_float(p.z), p.w, b2, j2);
        }
        sidx[tid] = j2;
    }
    __syncthreads();

    // gather: 8 rows of 256 floats; 32 threads per row, 2 float4 each
    int qi = tid >> 5;
    int cj = tid & 31;
    int row = sidx[qi];
    const float4* sp = (const float4*)(feats + (size_t)row * C_F);
    float4* dp = (float4*)(out + ((size_t)side * M_Q + q0 + qi) * (size_t)C_F);
    dp[cj]      = sp[cj];
    dp[cj + 32] = sp[cj + 32];
}

extern "C" void kernel_launch(void* const* d_in, const int* in_sizes, int n_in,
                              void* d_out, int out_size, void* d_ws, size_t ws_size,
                              hipStream_t stream) {
    const float* src  = (const float*)d_in[0];
    const float* tgt  = (const float*)d_in[1];
    const float* c0   = (const float*)d_in[2];  // src_coords   (N,3)
    const float* c1   = (const float*)d_in[3];  // tgt_coords   (N,3)
    const float* sh0  = (const float*)d_in[4];  // src_shortcut (M,3)
    const float* sh1  = (const float*)d_in[5];  // tgt_shortcut (M,3)
    float* out = (float*)d_out;

    float4* pts4 = (float4*)d_ws;                                   // 1 MB
    int4*   part = (int4*)((char*)d_ws + (size_t)2 * (N_PTS / 2) * 2 * sizeof(float4));

    hipLaunchKernelGGL(pack_pairs, dim3(2 * (N_PTS / 2) / 256), dim3(256), 0, stream,
                       c0, c1, pts4);
    hipLaunchKernelGGL(pool_scan, dim3(2 * NQB * PS), dim3(256), 0, stream,
                       sh0, sh1, pts4, part);
    hipLaunchKernelGGL(merge_gather, dim3(2 * (M_Q / 8)), dim3(256), 0, stream,
                       src, tgt, part, out);
}